// Round 7
// baseline (899.015 us; speedup 1.0000x reference)
//
#include <hip/hip_runtime.h>
#include <hip/hip_bf16.h>

#define BATCH 8
#define CH    64
#define HH    112
#define WW    112
#define HW    (HH * WW)          // 12544
#define NP    (BATCH * HW)       // 100352 pixels
#define TAPS  25
#define MIDC  256
#define OPAD  28                 // w2t LDS row pad (transpose staging)

typedef float    vf4 __attribute__((ext_vector_type(4)));
typedef _Float16 h2  __attribute__((ext_vector_type(2)));

__device__ __forceinline__ float fdot2f(unsigned int a, unsigned int b, float c) {
#if __has_builtin(__builtin_amdgcn_fdot2)
  return __builtin_amdgcn_fdot2(__builtin_bit_cast(h2, a),
                                __builtin_bit_cast(h2, b), c, false); // v_dot2_f32_f16
#else
  h2 av = __builtin_bit_cast(h2, a), bv = __builtin_bit_cast(h2, b);
  return c + (float)av.x * (float)bv.x + (float)av.y * (float)bv.y;
#endif
}

__device__ __forceinline__ unsigned int pk_f16(float a, float b) {
  // v_cvt_pkrtz_f16_f32; builtin returns __fp16x2 — bit_cast to uint.
  return __builtin_bit_cast(unsigned int, __builtin_amdgcn_cvt_pkrtz(a, b));
}

// ---------------------------------------------------------------------------
// Kernel A: fold conv2 into conv1, store f16 packed for dot2:
//   wpk[tap][o][c] (f16)  =  sum_mid w2[o][mid] * w1[mid][c][tap]
// (adjacent c form the half2 channel-pairs phase 1 consumes).
// Thread t = ctap = c*25+tap: w1 reads coalesced; w2 transposed in LDS.
// Workspace: 40000 f16 (80,000 B) + beff 25 f32 = 80,100 B.
// ---------------------------------------------------------------------------
__global__ __launch_bounds__(256) void weff_kernel(
    const float* __restrict__ w1, const float* __restrict__ b1,
    const float* __restrict__ w2, const float* __restrict__ b2,
    _Float16* __restrict__ wpk, float* __restrict__ beff) {
  __shared__ __align__(16) float w2t[MIDC * OPAD];   // [mid][28]
  for (int e = threadIdx.x; e < TAPS * MIDC; e += 256) {
    int o = e / MIDC, mid = e % MIDC;                // e == w2 flat index
    w2t[mid * OPAD + o] = w2[e];
  }
  for (int e = threadIdx.x; e < MIDC * 3; e += 256)
    w2t[(e / 3) * OPAD + 25 + (e % 3)] = 0.f;
  __syncthreads();

  int t = blockIdx.x * 256 + threadIdx.x;            // ctap
  if (t < CH * TAPS) {
    int c = t / TAPS, tap = t % TAPS;
    vf4 acc[7];
    #pragma unroll
    for (int q = 0; q < 7; ++q) acc[q] = (vf4)0.f;
    const vf4* w2v = (const vf4*)w2t;
    #pragma unroll 4
    for (int mid = 0; mid < MIDC; ++mid) {
      float a = w1[(size_t)mid * (CH * TAPS) + t];   // coalesced
      vf4 av = {a, a, a, a};
      const vf4* row = w2v + mid * 7;
      #pragma unroll
      for (int q = 0; q < 7; ++q) acc[q] += av * row[q];
    }
    #pragma unroll
    for (int o = 0; o < TAPS; ++o)
      wpk[((size_t)tap * TAPS + o) * CH + c] = (_Float16)acc[o >> 2][o & 3];
  }
  if (blockIdx.x == 0 && threadIdx.x < TAPS) {
    int o = threadIdx.x;
    float bacc = b2[o];
    for (int mid = 0; mid < MIDC; ++mid) bacc += w2t[mid * OPAD + o] * b1[mid];
    beff[o] = bacc;
  }
}

// ---------------------------------------------------------------------------
// Kernel B: 1-wave blocks. Lane = (px 0..15, cg 0..3); each lane owns 4
// vertically-stacked pixels (rows h0..h0+3, same 16-wide column band) x 16 ch.
// Phase 1: f16 dot2 logits, weights tap-chunked through LDS as half2
// channel-pairs [tl][o][cc] (16 px-lanes broadcast, 4 cgs on disjoint banks:
// conflict-free). One 2x-b128 weight read feeds 32 dot2s -> VALU-bound.
// Shuffle cg-reduce, register softmax, fp32 apply. XCD swizzle: blockIdx&7.
// ---------------------------------------------------------------------------
__global__ __launch_bounds__(64, 2) void picanet_main(
    const float* __restrict__ x, const _Float16* __restrict__ wpk,
    const float* __restrict__ beff, float* __restrict__ out) {
  __shared__ __align__(16) uint4 sw4[1000];          // 5 taps x 25 o x 32 h2 = 16,000 B

  const int lane = threadIdx.x;                      // 64
  const int px = lane & 15, cg = lane >> 4;

  const int b     = blockIdx.x & 7;                  // XCD-aligned image
  const int strip = blockIdx.x >> 3;                 // 0..195
  const int wg = strip % 7, hq = strip / 7;          // 7 col-bands x 28 row-quads
  const int h0 = hq * 4;
  const int w_ = wg * 16 + px;

  const float* xc = x + ((size_t)b * CH + cg * 16) * HW;  // lane's ch plane 0

  float acc[4][TAPS];
  #pragma unroll
  for (int s = 0; s < 4; ++s)
    #pragma unroll
    for (int o = 0; o < TAPS; ++o) acc[s][o] = 0.f;

  unsigned int xpu[4][8];

  for (int chunk = 0; chunk < 5; ++chunk) {          // 5 taps per chunk (i = chunk)
    __syncthreads();
    {
      const uint4* src = (const uint4*)wpk + chunk * 1000;
      for (int e = lane; e < 1000; e += 64) sw4[e] = src[e];
    }
    __syncthreads();

    #pragma unroll 1
    for (int tl = 0; tl < 5; ++tl) {                 // j = tl
      const int xx  = w_ + 2 * tl - 4;
      const bool okx = (xx >= 0) & (xx < WW);
      #pragma unroll
      for (int s = 0; s < 4; ++s) {
        const int yy = h0 + s + 2 * chunk - 4;
        const bool ok = okx & (yy >= 0) & (yy < HH);
        const int offt = ok ? yy * WW + xx : 0;
        #pragma unroll
        for (int cc = 0; cc < 8; ++cc) {
          float a  = xc[(size_t)(2 * cc) * HW + offt];
          float bq = xc[(size_t)(2 * cc + 1) * HW + offt];
          unsigned int p = pk_f16(a, bq);
          xpu[s][cc] = ok ? p : 0u;
        }
      }
      const int rb = tl * TAPS * 8 + cg * 2;         // uint4 index of (tl, o=0)
      #pragma unroll
      for (int o = 0; o < TAPS; ++o) {
        uint4 u0 = sw4[rb + o * 8];
        uint4 u1 = sw4[rb + o * 8 + 1];
        unsigned int wu[8] = {u0.x, u0.y, u0.z, u0.w, u1.x, u1.y, u1.z, u1.w};
        #pragma unroll
        for (int s = 0; s < 4; ++s) {
          float a = acc[s][o];
          #pragma unroll
          for (int q = 0; q < 8; ++q)
            a = fdot2f(xpu[s][q], wu[q], a);
          acc[s][o] = a;
        }
      }
    }
  }

  // ---- cg-reduce (intra-wave): lanes px, px+16, px+32, px+48 ----
  #pragma unroll
  for (int s = 0; s < 4; ++s)
    #pragma unroll
    for (int o = 0; o < TAPS; ++o) {
      float v = acc[s][o];
      v += __shfl_xor(v, 16);
      v += __shfl_xor(v, 32);
      acc[s][o] = v + beff[o];
    }

  // ---- per-pixel softmax + fp32 apply ----
  #pragma unroll
  for (int s = 0; s < 4; ++s) {
    float m = acc[s][0];
    #pragma unroll
    for (int o = 1; o < TAPS; ++o) m = fmaxf(m, acc[s][o]);
    float sum = 0.f;
    #pragma unroll
    for (int o = 0; o < TAPS; ++o) { acc[s][o] = __expf(acc[s][o] - m); sum += acc[s][o]; }
    float inv = 1.f / sum;
    #pragma unroll
    for (int o = 0; o < TAPS; ++o) {                 // fold validity mask
      int i = o / 5, j = o % 5;                      // compile-time
      int yy = h0 + s + 2 * i - 4, xx = w_ + 2 * j - 4;
      bool ok = (yy >= 0) & (yy < HH) & (xx >= 0) & (xx < WW);
      acc[s][o] = ok ? acc[s][o] * inv : 0.f;
    }

    float o16[16];
    #pragma unroll
    for (int c = 0; c < 16; ++c) o16[c] = 0.f;
    #pragma unroll
    for (int o = 0; o < TAPS; ++o) {
      int i = o / 5, j = o % 5;
      int yy = h0 + s + 2 * i - 4, xx = w_ + 2 * j - 4;
      bool ok = (yy >= 0) & (yy < HH) & (xx >= 0) & (xx < WW);
      int offt = ok ? yy * WW + xx : 0;              // acc==0 masks invalid
      float sv = acc[s][o];
      #pragma unroll
      for (int c = 0; c < 16; ++c)
        o16[c] = fmaf(sv, xc[(size_t)c * HW + offt], o16[c]);
    }
    float* ob = out + ((size_t)b * CH + cg * 16) * HW + (size_t)(h0 + s) * WW + w_;
    #pragma unroll
    for (int c = 0; c < 16; ++c) ob[(size_t)c * HW] = o16[c];
  }
}

extern "C" void kernel_launch(void* const* d_in, const int* in_sizes, int n_in,
                              void* d_out, int out_size, void* d_ws, size_t ws_size,
                              hipStream_t stream) {
  const float* x  = (const float*)d_in[0];
  const float* w1 = (const float*)d_in[1];
  const float* b1 = (const float*)d_in[2];
  const float* w2 = (const float*)d_in[3];
  const float* b2 = (const float*)d_in[4];
  float* out = (float*)d_out;
  // Workspace: wpk f16 [25][25][64] = 80,000 B, then beff 100 B (80,100 total).
  _Float16* wpk  = (_Float16*)d_ws;
  float*    beff = (float*)((char*)d_ws + 80000);

  weff_kernel<<<(CH * TAPS + 255) / 256, 256, 0, stream>>>(w1, b1, w2, b2, wpk, beff);
  picanet_main<<<BATCH * (HW / 64), 64, 0, stream>>>(x, wpk, beff, out);
}